// Round 7
// baseline (203.937 us; speedup 1.0000x reference)
//
#include <hip/hip_runtime.h>
#include <hip/hip_bf16.h>
#include <math.h>

using bf16 = __hip_bfloat16;
typedef __bf16 bf16x8_t __attribute__((ext_vector_type(8)));
typedef float f32x4_t __attribute__((ext_vector_type(4)));

static __device__ __forceinline__ f32x4_t mfma16(bf16x8_t a, bf16x8_t b, f32x4_t c) {
    return __builtin_amdgcn_mfma_f32_16x16x32_bf16(a, b, c, 0, 0, 0);
}

#if __has_builtin(__builtin_amdgcn_exp2f)
#define EXP2F __builtin_amdgcn_exp2f
#else
#define EXP2F exp2f
#endif

static __device__ __forceinline__ void sincos_rev(float rev, float* s, float* c) {
    float f = rev - floorf(rev);
#if __has_builtin(__builtin_amdgcn_sinf) && __has_builtin(__builtin_amdgcn_cosf)
    *s = __builtin_amdgcn_sinf(f);
    *c = __builtin_amdgcn_cosf(f);
#else
    float th = f * 6.2831853071795864f;
    *s = __sinf(th); *c = __cosf(th);
#endif
}

// async global->LDS 16B per lane; LDS dest is wave-uniform base + lane*16
static __device__ __forceinline__ void async16(bf16* lds, const bf16* g) {
    __builtin_amdgcn_global_load_lds(
        (const __attribute__((address_space(1))) unsigned int*)g,
        (__attribute__((address_space(3))) unsigned int*)lds, 16, 0, 0);
}

// ---------------------------------------------------------------------------
// Inline input-dtype detection (uniform across all waves; proven R2-R6).
// 1 -> bf16, 0 -> fp32.
// ---------------------------------------------------------------------------
static __device__ __forceinline__ int detect_bf16(const unsigned short* u16) {
    const int lane = threadIdx.x & 63;
    int sane = 0;
#pragma unroll
    for (int j = 0; j < 4; ++j) {
        const unsigned short u = u16[2 * (lane * 4 + j)];
        const int e = (u >> 7) & 0xFF;
        if (u == 0 || (e >= 100 && e <= 150)) sane++;
    }
#pragma unroll
    for (int off = 1; off <= 32; off <<= 1) sane += __shfl_xor(sane, off);
    return (sane * 2 >= 256) ? 1 : 0;
}

static __device__ __forceinline__ float bias_at(const void* b, int i, int isbf) {
    return isbf ? __bfloat162float(((const bf16*)b)[i]) : ((const float*)b)[i];
}

// ---------------------------------------------------------------------------
// 64x64 transpose tile body (256 threads), for weight prep.
// ---------------------------------------------------------------------------
static __device__ __forceinline__ void transpose_tile(
    const void* in, bf16* out, int in_ld, int out_ld, int bx, int by,
    int isbf, bf16 (*tile)[72]) {
    const int c0 = bx * 64, r0 = by * 64;
    const int tid = threadIdx.x;
    for (int c = tid; c < 512; c += 256) {
        const int r = c >> 3, co = (c & 7) << 3;
        if (isbf) {
            *reinterpret_cast<float4*>(&tile[r][co]) =
                *reinterpret_cast<const float4*>((const bf16*)in + (size_t)(r0 + r) * in_ld + c0 + co);
        } else {
            const float* f = (const float*)in + (size_t)(r0 + r) * in_ld + c0 + co;
            const float4 a = *reinterpret_cast<const float4*>(f);
            const float4 b = *reinterpret_cast<const float4*>(f + 4);
            tile[r][co + 0] = __float2bfloat16(a.x); tile[r][co + 1] = __float2bfloat16(a.y);
            tile[r][co + 2] = __float2bfloat16(a.z); tile[r][co + 3] = __float2bfloat16(a.w);
            tile[r][co + 4] = __float2bfloat16(b.x); tile[r][co + 5] = __float2bfloat16(b.y);
            tile[r][co + 6] = __float2bfloat16(b.z); tile[r][co + 7] = __float2bfloat16(b.w);
        }
    }
    __syncthreads();
    for (int c = tid; c < 512; c += 256) {
        const int r = c >> 3, co = (c & 7) << 3;
        union { float4 v; bf16 e[8]; } u;
#pragma unroll
        for (int j = 0; j < 8; ++j) u.e[j] = tile[co + j][r];
        *reinterpret_cast<float4*>(out + (size_t)(c0 + r) * out_ld + r0 + co) = u.v;
    }
}

// ---------------------------------------------------------------------------
// Fused prep: [0,432) w_attn^T; [432,576) w_proj^T; [576,2112) cast x.
// ---------------------------------------------------------------------------
__global__ __launch_bounds__(256) void prep_kernel(
    const void* __restrict__ x, const void* __restrict__ w_attn,
    const void* __restrict__ w_proj, bf16* __restrict__ xb,
    bf16* __restrict__ wAT, bf16* __restrict__ wPT) {
    __shared__ bf16 tile[64][72];
    const int isbf = detect_bf16((const unsigned short*)x);
    const int b = blockIdx.x;
    if (b < 432) {
        transpose_tile(w_attn, wAT, 2304, 768, b % 36, b / 36, isbf, tile);
    } else if (b < 576) {
        const int bb = b - 432;
        transpose_tile(w_proj, wPT, 768, 768, bb % 12, bb / 12, isbf, tile);
    } else {
        const int i = ((b - 576) * 256 + threadIdx.x) * 8;
        if (isbf) {
            *reinterpret_cast<float4*>(xb + i) =
                *reinterpret_cast<const float4*>((const bf16*)x + i);
        } else {
            const float* f = (const float*)x + i;
            const float4 a = *reinterpret_cast<const float4*>(f);
            const float4 c = *reinterpret_cast<const float4*>(f + 4);
            union { float4 v; bf16 e[8]; } u;
            u.e[0] = __float2bfloat16(a.x); u.e[1] = __float2bfloat16(a.y);
            u.e[2] = __float2bfloat16(a.z); u.e[3] = __float2bfloat16(a.w);
            u.e[4] = __float2bfloat16(c.x); u.e[5] = __float2bfloat16(c.y);
            u.e[6] = __float2bfloat16(c.z); u.e[7] = __float2bfloat16(c.w);
            *reinterpret_cast<float4*>(xb + i) = u.v;
        }
    }
}

// ---------------------------------------------------------------------------
// Async-staged MFMA bf16 GEMM, MT x 128 tile (MT = MI*32), BK=64, 256 thr.
// mode 1 (qkv): cols<1536 get bias+RoPE epilogue (q scaled 0.125*log2e) into
// C; v-cols (>=1536) are written ONLY as kappa-transposed Vt (LDS retile).
// mode 0 (proj): bias epilogue, optional fp32 store.
// ---------------------------------------------------------------------------
template <int MI>
__global__ __launch_bounds__(256, MI == 4 ? 3 : 4) void gemm_kernel(
    const bf16* __restrict__ A, const bf16* __restrict__ Bt,
    const void* __restrict__ bias, bf16* __restrict__ C,
    bf16* __restrict__ VtOut, const unsigned short* __restrict__ xdet,
    int N, int K, int mode, int flexout) {
    constexpr int MT = MI * 32;
    __shared__ bf16 smem[(MT + 128) * 64];
    bf16* sa = smem;
    bf16* sb = smem + MT * 64;
    const int tid = threadIdx.x, lane = tid & 63, w = tid >> 6;
    const int wm = w >> 1, wn = w & 1, quad = lane >> 4, l16 = lane & 15;
    const int m0 = blockIdx.y * MT, n0 = blockIdx.x * 128;
    const int strow = lane >> 3, stslot = lane & 7;

    const bf16* ag[MI]; const bf16* bgp[4];
#pragma unroll
    for (int i = 0; i < MI; ++i) {
        const int r = (w * MI + i) * 8 + strow;
        ag[i] = A + (size_t)(m0 + r) * K + (stslot ^ (r & 7)) * 8;
    }
#pragma unroll
    for (int i = 0; i < 4; ++i) {
        const int r = (w * 4 + i) * 8 + strow;
        bgp[i] = Bt + (size_t)(n0 + r) * K + (stslot ^ (r & 7)) * 8;
    }

    f32x4_t acc[MI][4];
#pragma unroll
    for (int i = 0; i < MI; ++i)
#pragma unroll
        for (int j = 0; j < 4; ++j) acc[i][j] = (f32x4_t){0.f, 0.f, 0.f, 0.f};

    for (int k0 = 0; k0 < K; k0 += 64) {
        __syncthreads();
#pragma unroll
        for (int i = 0; i < MI; ++i) async16(&sa[(w * MI + i) * 512], ag[i] + k0);
#pragma unroll
        for (int i = 0; i < 4; ++i)  async16(&sb[(w * 4 + i) * 512], bgp[i] + k0);
        __asm__ __volatile__("s_waitcnt vmcnt(0)" ::: "memory");
        __syncthreads();

#pragma unroll
        for (int kk = 0; kk < 2; ++kk) {
            bf16x8_t af[MI], bf_[4];
#pragma unroll
            for (int mi = 0; mi < MI; ++mi) {
                const int r = wm * (MI * 16) + mi * 16 + l16;
                af[mi] = *reinterpret_cast<const bf16x8_t*>(
                    &sa[r * 64 + (((kk * 4 + quad) ^ (r & 7)) << 3)]);
            }
#pragma unroll
            for (int ni = 0; ni < 4; ++ni) {
                const int r = wn * 64 + ni * 16 + l16;
                bf_[ni] = *reinterpret_cast<const bf16x8_t*>(
                    &sb[r * 64 + (((kk * 4 + quad) ^ (r & 7)) << 3)]);
            }
#pragma unroll
            for (int mi = 0; mi < MI; ++mi)
#pragma unroll
                for (int ni = 0; ni < 4; ++ni)
                    acc[mi][ni] = mfma16(af[mi], bf_[ni], acc[mi][ni]);
        }
    }

    const int isbf = detect_bf16(xdet);
    const int f32out = flexout && !isbf;
    const int colbase = n0 + wn * 64;
    const int rowbase = m0 + wm * (MI * 16);
    if (mode == 1 && colbase < 1536) {
        const bool isq = colbase < 768;
        const float QS = 0.18033688011112042f;  // 0.125 * log2(e)
#pragma unroll
        for (int ni = 0; ni < 2; ++ni) {
            const int d = ni * 16 + l16;
            const int col_lo = colbase + d, col_hi = col_lo + 32;
            const float blo = bias_at(bias, col_lo, isbf);
            const float bhi = bias_at(bias, col_hi, isbf);
            const float invf_rev = powf(10000.0f, -(float)d * (1.0f / 32.0f)) * 0.15915494309189535f;
#pragma unroll
            for (int mi = 0; mi < MI; ++mi) {
#pragma unroll
                for (int rg = 0; rg < 4; ++rg) {
                    const int t = rowbase + mi * 16 + quad * 4 + rg;
                    float sv, cv;
                    sincos_rev((float)t * invf_rev, &sv, &cv);
                    const float lo = acc[mi][ni][rg] + blo;
                    const float hi = acc[mi][ni + 2][rg] + bhi;
                    float nlo = lo * cv - hi * sv;
                    float nhi = hi * cv + lo * sv;
                    if (isq) { nlo *= QS; nhi *= QS; }
                    C[(size_t)t * N + col_lo] = __float2bfloat16(nlo);
                    C[(size_t)t * N + col_hi] = __float2bfloat16(nhi);
                }
            }
        }
    } else if (mode == 1) {
        // v-cols: write kappa-transposed Vt tile only (qkv v-region unused).
        // Vt[vr][tb*64+p] = v[tb*64 + kappa(p)][vr], kappa(p)=(p&3)*16+(p>>2).
        // Wave tile 64t x 64d; per-wave LDS retile region T[32][72] (2 passes).
        if constexpr (MI == 4) {
            __syncthreads();  // staging reads done; smem reused
            bf16* T = smem + w * 2304;
            const int vcb = colbase - 1536;
#pragma unroll
            for (int pass = 0; pass < 2; ++pass) {
                if (pass) __asm__ __volatile__("s_waitcnt lgkmcnt(0)" ::: "memory");
#pragma unroll
                for (int nl = 0; nl < 2; ++nl) {
                    const int ni = pass * 2 + nl;
                    const float b = bias_at(bias, colbase + ni * 16 + l16, isbf);
                    const int dh = nl * 16 + l16;
#pragma unroll
                    for (int rg = 0; rg < 4; ++rg) {
                        union { int2 v; bf16 e[4]; } pk;
#pragma unroll
                        for (int mi = 0; mi < 4; ++mi)
                            pk.e[mi] = __float2bfloat16(acc[mi][ni][rg] + b);
                        // t_local = mi*16+quad*4+rg = kappa(p) at p = quad*16+rg*4+mi
                        *reinterpret_cast<int2*>(&T[dh * 72 + quad * 16 + rg * 4]) = pk.v;
                    }
                }
                __asm__ __volatile__("s_waitcnt lgkmcnt(0)" ::: "memory");
#pragma unroll
                for (int s = 0; s < 4; ++s) {
                    const int dh = s * 8 + (lane >> 3);
                    const int pj = lane & 7;
                    const float4 vv = *reinterpret_cast<const float4*>(&T[dh * 72 + pj * 8]);
                    *reinterpret_cast<float4*>(
                        &VtOut[(size_t)(vcb + pass * 32 + dh) * 4096 + rowbase + pj * 8]) = vv;
                }
            }
        }
    } else {
#pragma unroll
        for (int ni = 0; ni < 4; ++ni) {
            const int col = colbase + ni * 16 + l16;
            const float b = bias_at(bias, col, isbf);
#pragma unroll
            for (int mi = 0; mi < MI; ++mi) {
#pragma unroll
                for (int rg = 0; rg < 4; ++rg) {
                    const int t = rowbase + mi * 16 + quad * 4 + rg;
                    const float v = acc[mi][ni][rg] + b;
                    if (f32out) ((float*)C)[(size_t)t * N + col] = v;
                    else        C[(size_t)t * N + col] = __float2bfloat16(v);
                }
            }
        }
    }
}

// ---------------------------------------------------------------------------
// Split-K causal flash attention, softmax-without-max (R5) + K double-buffer
// DMA prefetch + direct-global V fragments (kappa-Vt rows are contiguous).
// ---------------------------------------------------------------------------
__global__ __launch_bounds__(128, 3) void attn_kernel(
    const bf16* __restrict__ qkv, const bf16* __restrict__ Vt,
    bf16* __restrict__ ybuf, bf16* __restrict__ po, float* __restrict__ pl) {
    const int h = blockIdx.y;
    const int bx = blockIdx.x;
    int qt, c, nc;
    if (bx < 16)      { qt = bx;                 c = 0;             nc = 1; }
    else if (bx < 48) { qt = 16 + (bx - 16) / 2; c = (bx - 16) % 2; nc = 2; }
    else if (bx < 96) { qt = 32 + (bx - 48) / 3; c = (bx - 48) % 3; nc = 3; }
    else              { qt = 48 + (bx - 96) / 4; c = (bx - 96) % 4; nc = 4; }
    const int kt0 = c * 16;
    const int kt1 = min(kt0 + 16, qt + 1);

    const int tid = threadIdx.x, lane = tid & 63, w = tid >> 6;
    const int quad = lane >> 4, l16 = lane & 15, sw = l16 & 7;

    __shared__ bf16 Kt[2][4096];
    __shared__ bf16 Pt[2][2][16][72];

    const int strow = lane >> 3, stslot = lane & 7;
    const bf16* kg[4];
#pragma unroll
    for (int i = 0; i < 4; ++i) {
        const int key = (w * 4 + i) * 8 + strow;
        kg[i] = qkv + (size_t)key * 2304 + 768 + h * 64 + (stslot ^ (key & 7)) * 8;
    }
    const bf16* vbase = Vt + (size_t)(h * 64) * 4096;

    const int qbase = qt * 64 + w * 32;
    bf16x8_t qf[2][2];
#pragma unroll
    for (int f = 0; f < 2; ++f)
#pragma unroll
        for (int kc = 0; kc < 2; ++kc)
            qf[f][kc] = *reinterpret_cast<const bf16x8_t*>(
                qkv + (size_t)(qbase + f * 16 + l16) * 2304 + h * 64 + kc * 32 + quad * 8);

    f32x4_t o[2][4];
#pragma unroll
    for (int f = 0; f < 2; ++f)
#pragma unroll
        for (int dt = 0; dt < 4; ++dt) o[f][dt] = (f32x4_t){0.f, 0.f, 0.f, 0.f};
    float l_i[2][4] = {{0.f, 0.f, 0.f, 0.f}, {0.f, 0.f, 0.f, 0.f}};

    // stage K(kt0) into buf 0
#pragma unroll
    for (int i = 0; i < 4; ++i)
        async16(&Kt[0][(w * 4 + i) * 512], kg[i] + (size_t)kt0 * 64 * 2304);
    __asm__ __volatile__("s_waitcnt vmcnt(0)" ::: "memory");
    __syncthreads();

    for (int kt = kt0; kt < kt1; ++kt) {
        const int b = (kt - kt0) & 1;
        if (kt + 1 < kt1) {  // prefetch next K tile into other buffer
#pragma unroll
            for (int i = 0; i < 4; ++i)
                async16(&Kt[b ^ 1][(w * 4 + i) * 512], kg[i] + (size_t)(kt + 1) * 64 * 2304);
        }
        // V fragments direct from global (issued early, used at iter end)
        bf16x8_t vf[2][4];
#pragma unroll
        for (int kc = 0; kc < 2; ++kc)
#pragma unroll
            for (int dt = 0; dt < 4; ++dt)
                vf[kc][dt] = *reinterpret_cast<const bf16x8_t*>(
                    vbase + (size_t)(dt * 16 + l16) * 4096 + kt * 64 + kc * 32 + quad * 8);

        bf16x8_t kf[2][4];
#pragma unroll
        for (int kc = 0; kc < 2; ++kc)
#pragma unroll
            for (int ct = 0; ct < 4; ++ct)
                kf[kc][ct] = *reinterpret_cast<const bf16x8_t*>(
                    &Kt[b][((ct * 16 + l16) << 6) + (((kc * 4 + quad) ^ sw) << 3)]);

        f32x4_t s[2][4];
#pragma unroll
        for (int f = 0; f < 2; ++f)
#pragma unroll
            for (int ct = 0; ct < 4; ++ct) {
                s[f][ct] = mfma16(qf[f][0], kf[0][ct], (f32x4_t){0.f, 0.f, 0.f, 0.f});
                s[f][ct] = mfma16(qf[f][1], kf[1][ct], s[f][ct]);
            }

        if (kt == qt) {  // diagonal: causal mask (exp2(-inf)=0)
#pragma unroll
            for (int f = 0; f < 2; ++f) {
                const int rowb = qbase + f * 16 + quad * 4;
#pragma unroll
                for (int ct = 0; ct < 4; ++ct) {
                    const int key = kt * 64 + ct * 16 + l16;
#pragma unroll
                    for (int rg = 0; rg < 4; ++rg)
                        if (key > rowb + rg) s[f][ct][rg] = -INFINITY;
                }
            }
        }

#pragma unroll
        for (int f = 0; f < 2; ++f)
#pragma unroll
            for (int ct = 0; ct < 4; ++ct)
#pragma unroll
                for (int rg = 0; rg < 4; ++rg) {
                    const float p = EXP2F(s[f][ct][rg]);
                    s[f][ct][rg] = p;
                    l_i[f][rg] += p;
                }

#pragma unroll
        for (int f = 0; f < 2; ++f)
#pragma unroll
            for (int rg = 0; rg < 4; ++rg) {
                union { int2 v; __hip_bfloat162 h2[2]; } pk;
                pk.h2[0] = __float22bfloat162_rn(float2{s[f][0][rg], s[f][1][rg]});
                pk.h2[1] = __float22bfloat162_rn(float2{s[f][2][rg], s[f][3][rg]});
                *reinterpret_cast<int2*>(&Pt[w][f][quad * 4 + rg][l16 * 4]) = pk.v;
            }
        __asm__ __volatile__("s_waitcnt lgkmcnt(0)" ::: "memory");

#pragma unroll
        for (int f = 0; f < 2; ++f)
#pragma unroll
            for (int kc = 0; kc < 2; ++kc) {
                const bf16x8_t pf =
                    *reinterpret_cast<const bf16x8_t*>(&Pt[w][f][l16][kc * 32 + quad * 8]);
#pragma unroll
                for (int dt = 0; dt < 4; ++dt)
                    o[f][dt] = mfma16(pf, vf[kc][dt], o[f][dt]);
            }

        // wait K prefetch (had whole iteration to land) + all waves done with Kt[b]
        __asm__ __volatile__("s_waitcnt vmcnt(0)" ::: "memory");
        __syncthreads();
    }

#pragma unroll
    for (int off = 1; off <= 8; off <<= 1)
#pragma unroll
        for (int f = 0; f < 2; ++f)
#pragma unroll
            for (int rg = 0; rg < 4; ++rg) l_i[f][rg] += __shfl_xor(l_i[f][rg], off);

    if (nc == 1) {
#pragma unroll
        for (int f = 0; f < 2; ++f) {
            float linv[4];
#pragma unroll
            for (int rg = 0; rg < 4; ++rg)
                linv[rg] = (l_i[f][rg] > 0.f) ? 1.0f / l_i[f][rg] : 0.f;
#pragma unroll
            for (int dt = 0; dt < 4; ++dt)
#pragma unroll
                for (int rg = 0; rg < 4; ++rg)
                    ybuf[(size_t)(qbase + f * 16 + quad * 4 + rg) * 768 + h * 64 + dt * 16 + l16] =
                        __float2bfloat16(o[f][dt][rg] * linv[rg]);
        }
    } else {
#pragma unroll
        for (int f = 0; f < 2; ++f) {
            float linv[4];
#pragma unroll
            for (int rg = 0; rg < 4; ++rg)
                linv[rg] = (l_i[f][rg] > 0.f) ? 1.0f / l_i[f][rg] : 0.f;
#pragma unroll
            for (int dt = 0; dt < 4; ++dt)
#pragma unroll
                for (int rg = 0; rg < 4; ++rg) {
                    const int row = qbase + f * 16 + quad * 4 + rg;
                    po[((size_t)((h << 12) + row) * 4 + c) * 64 + dt * 16 + l16] =
                        __float2bfloat16(o[f][dt][rg] * linv[rg]);
                }
            if (l16 == 0) {
#pragma unroll
                for (int rg = 0; rg < 4; ++rg) {
                    const int row = qbase + f * 16 + quad * 4 + rg;
                    pl[((h << 12) + row) * 4 + c] = l_i[f][rg];
                }
            }
        }
    }
}

// ---------------------------------------------------------------------------
// Combine split-K partials for rows >= 1024 (shared exp2-ref 0).
// ---------------------------------------------------------------------------
__global__ __launch_bounds__(256) void combine_kernel(
    const bf16* __restrict__ po, const float* __restrict__ pl,
    bf16* __restrict__ ybuf) {
    const int g = blockIdx.x * 256 + threadIdx.x;
    if (g >= 12 * 3072 * 64) return;
    const int d = g & 63;
    const int rr = (g >> 6) % 3072;
    const int h = g / (3072 * 64);
    const int r = 1024 + rr;
    const int nc = (r >> 6) / 16 + 1;  // 2..4
    const int base = ((h << 12) + r) * 4;
    float wsum = 0.f, acc = 0.f;
    for (int cc = 0; cc < nc; ++cc) {
        const float wgt = pl[base + cc];
        wsum += wgt;
        acc += wgt * __bfloat162float(po[(size_t)(base + cc) * 64 + d]);
    }
    ybuf[(size_t)r * 768 + h * 64 + d] = __float2bfloat16(acc / wsum);
}

// ---------------------------------------------------------------------------
extern "C" void kernel_launch(void* const* d_in, const int* in_sizes, int n_in,
                              void* d_out, int out_size, void* d_ws, size_t ws_size,
                              hipStream_t stream) {
    bf16* qkv  = (bf16*)d_ws;                  // 4096*2304 (v region unused)
    bf16* wAT  = qkv + (size_t)4096 * 2304;    // 2304*768
    bf16* wPT  = wAT + (size_t)2304 * 768;     // 768*768
    bf16* Vt   = wPT + (size_t)768 * 768;      // 768*4096 (kappa-permuted)
    bf16* ybuf = Vt + (size_t)768 * 4096;      // 4096*768
    bf16* xb   = ybuf + (size_t)4096 * 768;    // 4096*768
    bf16* po   = xb + (size_t)4096 * 768;      // 12*4096*4*64
    float* pl  = (float*)(po + (size_t)12 * 4096 * 4 * 64);  // 12*4096*4
    const unsigned short* xdet = (const unsigned short*)d_in[0];

    prep_kernel<<<2112, 256, 0, stream>>>(d_in[0], d_in[1], d_in[3], xb, wAT, wPT);
    // qkv = x @ w_attn + b_attn (RoPE fused); v-cols -> Vt directly
    gemm_kernel<4><<<dim3(18, 32), 256, 0, stream>>>(
        xb, wAT, d_in[2], qkv, Vt, xdet, 2304, 768, 1, 0);
    attn_kernel<<<dim3(160, 12), 128, 0, stream>>>(qkv, Vt, ybuf, po, pl);
    combine_kernel<<<9216, 256, 0, stream>>>(po, pl, ybuf);
    gemm_kernel<1><<<dim3(6, 128), 256, 0, stream>>>(
        ybuf, wPT, d_in[4], (bf16*)d_out, nullptr, xdet, 768, 768, 0, 1);
}

// Round 8
// 181.208 us; speedup vs baseline: 1.1254x; 1.1254x over previous
//
#include <hip/hip_runtime.h>
#include <hip/hip_bf16.h>
#include <math.h>

using bf16 = __hip_bfloat16;
typedef __bf16 bf16x8_t __attribute__((ext_vector_type(8)));
typedef float f32x4_t __attribute__((ext_vector_type(4)));

static __device__ __forceinline__ f32x4_t mfma16(bf16x8_t a, bf16x8_t b, f32x4_t c) {
    return __builtin_amdgcn_mfma_f32_16x16x32_bf16(a, b, c, 0, 0, 0);
}

#if __has_builtin(__builtin_amdgcn_exp2f)
#define EXP2F __builtin_amdgcn_exp2f
#else
#define EXP2F exp2f
#endif

static __device__ __forceinline__ void sincos_rev(float rev, float* s, float* c) {
    float f = rev - floorf(rev);
#if __has_builtin(__builtin_amdgcn_sinf) && __has_builtin(__builtin_amdgcn_cosf)
    *s = __builtin_amdgcn_sinf(f);
    *c = __builtin_amdgcn_cosf(f);
#else
    float th = f * 6.2831853071795864f;
    *s = __sinf(th); *c = __cosf(th);
#endif
}

// async global->LDS 16B per lane; LDS dest is wave-uniform base + lane*16
static __device__ __forceinline__ void async16(bf16* lds, const bf16* g) {
    __builtin_amdgcn_global_load_lds(
        (const __attribute__((address_space(1))) unsigned int*)g,
        (__attribute__((address_space(3))) unsigned int*)lds, 16, 0, 0);
}

// ---------------------------------------------------------------------------
// Inline input-dtype detection (uniform across all waves; proven R2-R7).
// 1 -> bf16, 0 -> fp32.
// ---------------------------------------------------------------------------
static __device__ __forceinline__ int detect_bf16(const unsigned short* u16) {
    const int lane = threadIdx.x & 63;
    int sane = 0;
#pragma unroll
    for (int j = 0; j < 4; ++j) {
        const unsigned short u = u16[2 * (lane * 4 + j)];
        const int e = (u >> 7) & 0xFF;
        if (u == 0 || (e >= 100 && e <= 150)) sane++;
    }
#pragma unroll
    for (int off = 1; off <= 32; off <<= 1) sane += __shfl_xor(sane, off);
    return (sane * 2 >= 256) ? 1 : 0;
}

static __device__ __forceinline__ float bias_at(const void* b, int i, int isbf) {
    return isbf ? __bfloat162float(((const bf16*)b)[i]) : ((const float*)b)[i];
}

// ---------------------------------------------------------------------------
// 64x64 transpose tile body (256 threads), for weight prep.
// ---------------------------------------------------------------------------
static __device__ __forceinline__ void transpose_tile(
    const void* in, bf16* out, int in_ld, int out_ld, int bx, int by,
    int isbf, bf16 (*tile)[72]) {
    const int c0 = bx * 64, r0 = by * 64;
    const int tid = threadIdx.x;
    for (int c = tid; c < 512; c += 256) {
        const int r = c >> 3, co = (c & 7) << 3;
        if (isbf) {
            *reinterpret_cast<float4*>(&tile[r][co]) =
                *reinterpret_cast<const float4*>((const bf16*)in + (size_t)(r0 + r) * in_ld + c0 + co);
        } else {
            const float* f = (const float*)in + (size_t)(r0 + r) * in_ld + c0 + co;
            const float4 a = *reinterpret_cast<const float4*>(f);
            const float4 b = *reinterpret_cast<const float4*>(f + 4);
            tile[r][co + 0] = __float2bfloat16(a.x); tile[r][co + 1] = __float2bfloat16(a.y);
            tile[r][co + 2] = __float2bfloat16(a.z); tile[r][co + 3] = __float2bfloat16(a.w);
            tile[r][co + 4] = __float2bfloat16(b.x); tile[r][co + 5] = __float2bfloat16(b.y);
            tile[r][co + 6] = __float2bfloat16(b.z); tile[r][co + 7] = __float2bfloat16(b.w);
        }
    }
    __syncthreads();
    for (int c = tid; c < 512; c += 256) {
        const int r = c >> 3, co = (c & 7) << 3;
        union { float4 v; bf16 e[8]; } u;
#pragma unroll
        for (int j = 0; j < 8; ++j) u.e[j] = tile[co + j][r];
        *reinterpret_cast<float4*>(out + (size_t)(c0 + r) * out_ld + r0 + co) = u.v;
    }
}

// ---------------------------------------------------------------------------
// Fused prep: [0,432) w_attn^T; [432,576) w_proj^T; [576,2112) cast x.
// ---------------------------------------------------------------------------
__global__ __launch_bounds__(256) void prep_kernel(
    const void* __restrict__ x, const void* __restrict__ w_attn,
    const void* __restrict__ w_proj, bf16* __restrict__ xb,
    bf16* __restrict__ wAT, bf16* __restrict__ wPT) {
    __shared__ bf16 tile[64][72];
    const int isbf = detect_bf16((const unsigned short*)x);
    const int b = blockIdx.x;
    if (b < 432) {
        transpose_tile(w_attn, wAT, 2304, 768, b % 36, b / 36, isbf, tile);
    } else if (b < 576) {
        const int bb = b - 432;
        transpose_tile(w_proj, wPT, 768, 768, bb % 12, bb / 12, isbf, tile);
    } else {
        const int i = ((b - 576) * 256 + threadIdx.x) * 8;
        if (isbf) {
            *reinterpret_cast<float4*>(xb + i) =
                *reinterpret_cast<const float4*>((const bf16*)x + i);
        } else {
            const float* f = (const float*)x + i;
            const float4 a = *reinterpret_cast<const float4*>(f);
            const float4 c = *reinterpret_cast<const float4*>(f + 4);
            union { float4 v; bf16 e[8]; } u;
            u.e[0] = __float2bfloat16(a.x); u.e[1] = __float2bfloat16(a.y);
            u.e[2] = __float2bfloat16(a.z); u.e[3] = __float2bfloat16(a.w);
            u.e[4] = __float2bfloat16(c.x); u.e[5] = __float2bfloat16(c.y);
            u.e[6] = __float2bfloat16(c.z); u.e[7] = __float2bfloat16(c.w);
            *reinterpret_cast<float4*>(xb + i) = u.v;
        }
    }
}

// ---------------------------------------------------------------------------
// Async-staged MFMA bf16 GEMM, MT x 128 tile (MT = MI*32), BK=64, 256 thr.
// mode 1 (qkv): cols<1536 bias+RoPE into C; v-cols -> kappa-transposed Vt.
// mode 0 (proj): bias epilogue, optional fp32 store.
// ---------------------------------------------------------------------------
template <int MI>
__global__ __launch_bounds__(256, MI == 4 ? 3 : 4) void gemm_kernel(
    const bf16* __restrict__ A, const bf16* __restrict__ Bt,
    const void* __restrict__ bias, bf16* __restrict__ C,
    bf16* __restrict__ VtOut, const unsigned short* __restrict__ xdet,
    int N, int K, int mode, int flexout) {
    constexpr int MT = MI * 32;
    __shared__ bf16 smem[(MT + 128) * 64];
    bf16* sa = smem;
    bf16* sb = smem + MT * 64;
    const int tid = threadIdx.x, lane = tid & 63, w = tid >> 6;
    const int wm = w >> 1, wn = w & 1, quad = lane >> 4, l16 = lane & 15;
    const int m0 = blockIdx.y * MT, n0 = blockIdx.x * 128;
    const int strow = lane >> 3, stslot = lane & 7;

    const bf16* ag[MI]; const bf16* bgp[4];
#pragma unroll
    for (int i = 0; i < MI; ++i) {
        const int r = (w * MI + i) * 8 + strow;
        ag[i] = A + (size_t)(m0 + r) * K + (stslot ^ (r & 7)) * 8;
    }
#pragma unroll
    for (int i = 0; i < 4; ++i) {
        const int r = (w * 4 + i) * 8 + strow;
        bgp[i] = Bt + (size_t)(n0 + r) * K + (stslot ^ (r & 7)) * 8;
    }

    f32x4_t acc[MI][4];
#pragma unroll
    for (int i = 0; i < MI; ++i)
#pragma unroll
        for (int j = 0; j < 4; ++j) acc[i][j] = (f32x4_t){0.f, 0.f, 0.f, 0.f};

    for (int k0 = 0; k0 < K; k0 += 64) {
        __syncthreads();
#pragma unroll
        for (int i = 0; i < MI; ++i) async16(&sa[(w * MI + i) * 512], ag[i] + k0);
#pragma unroll
        for (int i = 0; i < 4; ++i)  async16(&sb[(w * 4 + i) * 512], bgp[i] + k0);
        __asm__ __volatile__("s_waitcnt vmcnt(0)" ::: "memory");
        __syncthreads();

#pragma unroll
        for (int kk = 0; kk < 2; ++kk) {
            bf16x8_t af[MI], bf_[4];
#pragma unroll
            for (int mi = 0; mi < MI; ++mi) {
                const int r = wm * (MI * 16) + mi * 16 + l16;
                af[mi] = *reinterpret_cast<const bf16x8_t*>(
                    &sa[r * 64 + (((kk * 4 + quad) ^ (r & 7)) << 3)]);
            }
#pragma unroll
            for (int ni = 0; ni < 4; ++ni) {
                const int r = wn * 64 + ni * 16 + l16;
                bf_[ni] = *reinterpret_cast<const bf16x8_t*>(
                    &sb[r * 64 + (((kk * 4 + quad) ^ (r & 7)) << 3)]);
            }
#pragma unroll
            for (int mi = 0; mi < MI; ++mi)
#pragma unroll
                for (int ni = 0; ni < 4; ++ni)
                    acc[mi][ni] = mfma16(af[mi], bf_[ni], acc[mi][ni]);
        }
    }

    const int isbf = detect_bf16(xdet);
    const int f32out = flexout && !isbf;
    const int colbase = n0 + wn * 64;
    const int rowbase = m0 + wm * (MI * 16);
    if (mode == 1 && colbase < 1536) {
        const bool isq = colbase < 768;
        const float QS = 0.18033688011112042f;  // 0.125 * log2(e)
#pragma unroll
        for (int ni = 0; ni < 2; ++ni) {
            const int d = ni * 16 + l16;
            const int col_lo = colbase + d, col_hi = col_lo + 32;
            const float blo = bias_at(bias, col_lo, isbf);
            const float bhi = bias_at(bias, col_hi, isbf);
            const float invf_rev = powf(10000.0f, -(float)d * (1.0f / 32.0f)) * 0.15915494309189535f;
#pragma unroll
            for (int mi = 0; mi < MI; ++mi) {
#pragma unroll
                for (int rg = 0; rg < 4; ++rg) {
                    const int t = rowbase + mi * 16 + quad * 4 + rg;
                    float sv, cv;
                    sincos_rev((float)t * invf_rev, &sv, &cv);
                    const float lo = acc[mi][ni][rg] + blo;
                    const float hi = acc[mi][ni + 2][rg] + bhi;
                    float nlo = lo * cv - hi * sv;
                    float nhi = hi * cv + lo * sv;
                    if (isq) { nlo *= QS; nhi *= QS; }
                    C[(size_t)t * N + col_lo] = __float2bfloat16(nlo);
                    C[(size_t)t * N + col_hi] = __float2bfloat16(nhi);
                }
            }
        }
    } else if (mode == 1) {
        // v-cols: write kappa-transposed Vt tile only.
        if constexpr (MI == 4) {
            __syncthreads();  // staging reads done; smem reused
            bf16* T = smem + w * 2304;
            const int vcb = colbase - 1536;
#pragma unroll
            for (int pass = 0; pass < 2; ++pass) {
                if (pass) __asm__ __volatile__("s_waitcnt lgkmcnt(0)" ::: "memory");
#pragma unroll
                for (int nl = 0; nl < 2; ++nl) {
                    const int ni = pass * 2 + nl;
                    const float b = bias_at(bias, colbase + ni * 16 + l16, isbf);
                    const int dh = nl * 16 + l16;
#pragma unroll
                    for (int rg = 0; rg < 4; ++rg) {
                        union { int2 v; bf16 e[4]; } pk;
#pragma unroll
                        for (int mi = 0; mi < 4; ++mi)
                            pk.e[mi] = __float2bfloat16(acc[mi][ni][rg] + b);
                        *reinterpret_cast<int2*>(&T[dh * 72 + quad * 16 + rg * 4]) = pk.v;
                    }
                }
                __asm__ __volatile__("s_waitcnt lgkmcnt(0)" ::: "memory");
#pragma unroll
                for (int s = 0; s < 4; ++s) {
                    const int dh = s * 8 + (lane >> 3);
                    const int pj = lane & 7;
                    const float4 vv = *reinterpret_cast<const float4*>(&T[dh * 72 + pj * 8]);
                    *reinterpret_cast<float4*>(
                        &VtOut[(size_t)(vcb + pass * 32 + dh) * 4096 + rowbase + pj * 8]) = vv;
                }
            }
        }
    } else {
#pragma unroll
        for (int ni = 0; ni < 4; ++ni) {
            const int col = colbase + ni * 16 + l16;
            const float b = bias_at(bias, col, isbf);
#pragma unroll
            for (int mi = 0; mi < MI; ++mi) {
#pragma unroll
                for (int rg = 0; rg < 4; ++rg) {
                    const int t = rowbase + mi * 16 + quad * 4 + rg;
                    const float v = acc[mi][ni][rg] + b;
                    if (f32out) ((float*)C)[(size_t)t * N + col] = v;
                    else        C[(size_t)t * N + col] = __float2bfloat16(v);
                }
            }
        }
    }
}

// ---------------------------------------------------------------------------
// Split-K causal flash attention, softmax-without-max (R5).
// Single-buffered K/V LDS with read-first pipeline: fragments are ds_read
// into registers at iteration top (barrier pins them there), THEN next tile's
// DMA is issued into the same buffers and lands during compute. No serial
// DMA->wait->compute segment. LDS 20.5 KB.
// ---------------------------------------------------------------------------
__global__ __launch_bounds__(128, 3) void attn_kernel(
    const bf16* __restrict__ qkv, const bf16* __restrict__ Vt,
    bf16* __restrict__ ybuf, bf16* __restrict__ po, float* __restrict__ pl) {
    const int h = blockIdx.y;
    const int bx = blockIdx.x;
    int qt, c, nc;
    if (bx < 16)      { qt = bx;                 c = 0;             nc = 1; }
    else if (bx < 48) { qt = 16 + (bx - 16) / 2; c = (bx - 16) % 2; nc = 2; }
    else if (bx < 96) { qt = 32 + (bx - 48) / 3; c = (bx - 48) % 3; nc = 3; }
    else              { qt = 48 + (bx - 96) / 4; c = (bx - 96) % 4; nc = 4; }
    const int kt0 = c * 16;
    const int kt1 = min(kt0 + 16, qt + 1);

    const int tid = threadIdx.x, lane = tid & 63, w = tid >> 6;
    const int quad = lane >> 4, l16 = lane & 15, sw = l16 & 7;

    __shared__ bf16 Kt[4096];
    __shared__ bf16 Vs[4096];
    __shared__ bf16 Pt[2][2][16][72];

    const int strow = lane >> 3, stslot = lane & 7;
    const bf16* kg[4]; const bf16* vg[4];
#pragma unroll
    for (int i = 0; i < 4; ++i) {
        const int ch = w * 4 + i;
        const int key = ch * 8 + strow;
        kg[i] = qkv + (size_t)key * 2304 + 768 + h * 64 + (stslot ^ (key & 7)) * 8;
        const int d = ch * 8 + strow;
        vg[i] = Vt + (size_t)(h * 64 + d) * 4096 + (stslot ^ (d & 7)) * 8;
    }

    const int qbase = qt * 64 + w * 32;
    bf16x8_t qf[2][2];
#pragma unroll
    for (int f = 0; f < 2; ++f)
#pragma unroll
        for (int kc = 0; kc < 2; ++kc)
            qf[f][kc] = *reinterpret_cast<const bf16x8_t*>(
                qkv + (size_t)(qbase + f * 16 + l16) * 2304 + h * 64 + kc * 32 + quad * 8);

    f32x4_t o[2][4];
#pragma unroll
    for (int f = 0; f < 2; ++f)
#pragma unroll
        for (int dt = 0; dt < 4; ++dt) o[f][dt] = (f32x4_t){0.f, 0.f, 0.f, 0.f};
    float l_i[2][4] = {{0.f, 0.f, 0.f, 0.f}, {0.f, 0.f, 0.f, 0.f}};

    // stage tile kt0
#pragma unroll
    for (int i = 0; i < 4; ++i) {
        async16(&Kt[(w * 4 + i) * 512], kg[i] + (size_t)kt0 * 64 * 2304);
        async16(&Vs[(w * 4 + i) * 512], vg[i] + (size_t)kt0 * 64);
    }
    __asm__ __volatile__("s_waitcnt vmcnt(0)" ::: "memory");
    __syncthreads();

    for (int kt = kt0; kt < kt1; ++kt) {
        // read ALL K/V fragments into registers first (cannot sink past barrier)
        bf16x8_t kf[2][4], vf[2][4];
#pragma unroll
        for (int kc = 0; kc < 2; ++kc)
#pragma unroll
            for (int ct = 0; ct < 4; ++ct)
                kf[kc][ct] = *reinterpret_cast<const bf16x8_t*>(
                    &Kt[((ct * 16 + l16) << 6) + (((kc * 4 + quad) ^ sw) << 3)]);
#pragma unroll
        for (int kc = 0; kc < 2; ++kc)
#pragma unroll
            for (int dt = 0; dt < 4; ++dt)
                vf[kc][dt] = *reinterpret_cast<const bf16x8_t*>(
                    &Vs[((dt * 16 + l16) << 6) + (((kc * 4 + quad) ^ sw) << 3)]);
        __syncthreads();  // all waves have consumed Kt/Vs

        if (kt + 1 < kt1) {  // prefetch next tile into same buffers during compute
#pragma unroll
            for (int i = 0; i < 4; ++i) {
                async16(&Kt[(w * 4 + i) * 512], kg[i] + (size_t)(kt + 1) * 64 * 2304);
                async16(&Vs[(w * 4 + i) * 512], vg[i] + (size_t)(kt + 1) * 64);
            }
        }

        f32x4_t s[2][4];
#pragma unroll
        for (int f = 0; f < 2; ++f)
#pragma unroll
            for (int ct = 0; ct < 4; ++ct) {
                s[f][ct] = mfma16(qf[f][0], kf[0][ct], (f32x4_t){0.f, 0.f, 0.f, 0.f});
                s[f][ct] = mfma16(qf[f][1], kf[1][ct], s[f][ct]);
            }

        if (kt == qt) {  // diagonal: causal mask (exp2(-inf)=0)
#pragma unroll
            for (int f = 0; f < 2; ++f) {
                const int rowb = qbase + f * 16 + quad * 4;
#pragma unroll
                for (int ct = 0; ct < 4; ++ct) {
                    const int key = kt * 64 + ct * 16 + l16;
#pragma unroll
                    for (int rg = 0; rg < 4; ++rg)
                        if (key > rowb + rg) s[f][ct][rg] = -INFINITY;
                }
            }
        }

#pragma unroll
        for (int f = 0; f < 2; ++f)
#pragma unroll
            for (int ct = 0; ct < 4; ++ct)
#pragma unroll
                for (int rg = 0; rg < 4; ++rg) {
                    const float p = EXP2F(s[f][ct][rg]);
                    s[f][ct][rg] = p;
                    l_i[f][rg] += p;
                }

#pragma unroll
        for (int f = 0; f < 2; ++f)
#pragma unroll
            for (int rg = 0; rg < 4; ++rg) {
                union { int2 v; __hip_bfloat162 h2[2]; } pk;
                pk.h2[0] = __float22bfloat162_rn(float2{s[f][0][rg], s[f][1][rg]});
                pk.h2[1] = __float22bfloat162_rn(float2{s[f][2][rg], s[f][3][rg]});
                *reinterpret_cast<int2*>(&Pt[w][f][quad * 4 + rg][l16 * 4]) = pk.v;
            }
        __asm__ __volatile__("s_waitcnt lgkmcnt(0)" ::: "memory");

#pragma unroll
        for (int f = 0; f < 2; ++f)
#pragma unroll
            for (int kc = 0; kc < 2; ++kc) {
                const bf16x8_t pf =
                    *reinterpret_cast<const bf16x8_t*>(&Pt[w][f][l16][kc * 32 + quad * 8]);
#pragma unroll
                for (int dt = 0; dt < 4; ++dt)
                    o[f][dt] = mfma16(pf, vf[kc][dt], o[f][dt]);
            }

        // prefetch (issued a full iteration ago) must have landed for all waves
        __asm__ __volatile__("s_waitcnt vmcnt(0)" ::: "memory");
        __syncthreads();
    }

#pragma unroll
    for (int off = 1; off <= 8; off <<= 1)
#pragma unroll
        for (int f = 0; f < 2; ++f)
#pragma unroll
            for (int rg = 0; rg < 4; ++rg) l_i[f][rg] += __shfl_xor(l_i[f][rg], off);

    if (nc == 1) {
#pragma unroll
        for (int f = 0; f < 2; ++f) {
            float linv[4];
#pragma unroll
            for (int rg = 0; rg < 4; ++rg)
                linv[rg] = (l_i[f][rg] > 0.f) ? 1.0f / l_i[f][rg] : 0.f;
#pragma unroll
            for (int dt = 0; dt < 4; ++dt)
#pragma unroll
                for (int rg = 0; rg < 4; ++rg)
                    ybuf[(size_t)(qbase + f * 16 + quad * 4 + rg) * 768 + h * 64 + dt * 16 + l16] =
                        __float2bfloat16(o[f][dt][rg] * linv[rg]);
        }
    } else {
#pragma unroll
        for (int f = 0; f < 2; ++f) {
            float linv[4];
#pragma unroll
            for (int rg = 0; rg < 4; ++rg)
                linv[rg] = (l_i[f][rg] > 0.f) ? 1.0f / l_i[f][rg] : 0.f;
#pragma unroll
            for (int dt = 0; dt < 4; ++dt)
#pragma unroll
                for (int rg = 0; rg < 4; ++rg) {
                    const int row = qbase + f * 16 + quad * 4 + rg;
                    po[((size_t)((h << 12) + row) * 4 + c) * 64 + dt * 16 + l16] =
                        __float2bfloat16(o[f][dt][rg] * linv[rg]);
                }
            if (l16 == 0) {
#pragma unroll
                for (int rg = 0; rg < 4; ++rg) {
                    const int row = qbase + f * 16 + quad * 4 + rg;
                    pl[((h << 12) + row) * 4 + c] = l_i[f][rg];
                }
            }
        }
    }
}

// ---------------------------------------------------------------------------
// Combine split-K partials for rows >= 1024 (shared exp2-ref 0).
// ---------------------------------------------------------------------------
__global__ __launch_bounds__(256) void combine_kernel(
    const bf16* __restrict__ po, const float* __restrict__ pl,
    bf16* __restrict__ ybuf) {
    const int g = blockIdx.x * 256 + threadIdx.x;
    if (g >= 12 * 3072 * 64) return;
    const int d = g & 63;
    const int rr = (g >> 6) % 3072;
    const int h = g / (3072 * 64);
    const int r = 1024 + rr;
    const int nc = (r >> 6) / 16 + 1;  // 2..4
    const int base = ((h << 12) + r) * 4;
    float wsum = 0.f, acc = 0.f;
    for (int cc = 0; cc < nc; ++cc) {
        const float wgt = pl[base + cc];
        wsum += wgt;
        acc += wgt * __bfloat162float(po[(size_t)(base + cc) * 64 + d]);
    }
    ybuf[(size_t)r * 768 + h * 64 + d] = __float2bfloat16(acc / wsum);
}

// ---------------------------------------------------------------------------
extern "C" void kernel_launch(void* const* d_in, const int* in_sizes, int n_in,
                              void* d_out, int out_size, void* d_ws, size_t ws_size,
                              hipStream_t stream) {
    bf16* qkv  = (bf16*)d_ws;                  // 4096*2304 (v region unused)
    bf16* wAT  = qkv + (size_t)4096 * 2304;    // 2304*768
    bf16* wPT  = wAT + (size_t)2304 * 768;     // 768*768
    bf16* Vt   = wPT + (size_t)768 * 768;      // 768*4096 (kappa-permuted)
    bf16* ybuf = Vt + (size_t)768 * 4096;      // 4096*768
    bf16* xb   = ybuf + (size_t)4096 * 768;    // 4096*768
    bf16* po   = xb + (size_t)4096 * 768;      // 12*4096*4*64
    float* pl  = (float*)(po + (size_t)12 * 4096 * 4 * 64);  // 12*4096*4
    const unsigned short* xdet = (const unsigned short*)d_in[0];

    prep_kernel<<<2112, 256, 0, stream>>>(d_in[0], d_in[1], d_in[3], xb, wAT, wPT);
    // qkv = x @ w_attn + b_attn (RoPE fused); v-cols -> Vt directly
    gemm_kernel<4><<<dim3(18, 32), 256, 0, stream>>>(
        xb, wAT, d_in[2], qkv, Vt, xdet, 2304, 768, 1, 0);
    attn_kernel<<<dim3(160, 12), 128, 0, stream>>>(qkv, Vt, ybuf, po, pl);
    combine_kernel<<<9216, 256, 0, stream>>>(po, pl, ybuf);
    gemm_kernel<1><<<dim3(6, 128), 256, 0, stream>>>(
        ybuf, wPT, d_in[4], (bf16*)d_out, nullptr, xdet, 768, 768, 0, 1);
}